// Round 12
// baseline (290.119 us; speedup 1.0000x reference)
//
#include <hip/hip_runtime.h>
#include <cmath>

static constexpr int B_  = 16;
static constexpr int N_  = 2048;
static constexpr int NT_ = 32768;
static constexpr int E_  = 524288;

// Workspace layout (float-element offsets)
static constexpr size_t OFF_HSC    = 0;          // NT_*64
static constexpr size_t OFF_XD     = 2097152;    // NT_*128
static constexpr size_t OFF_SWS    = 6291456;    // NT_*32
static constexpr size_t OFF_PART   = 7340032;    // 512*32*128
static constexpr size_t OFF_GSP    = 9437184;    // 128*64
static constexpr size_t OFF_GSP2   = 9445376;    // 128*64
static constexpr size_t OFF_SSP    = 9453568;    // 512*1024
static constexpr size_t OFF_CAP    = 9977856;    // 512*32
static constexpr size_t OFF_CSP    = 9994240;    // 512*32
static constexpr size_t OFF_SPECP  = 10010624;   // 512
static constexpr size_t OFF_DINV   = 10011136;   // NT_
// int region
static constexpr size_t OFF_IHIN   = 10043904;   // 262144 per-partition in-hists
static constexpr size_t OFF_IHOUT  = 10306048;   // 262144 per-partition out-hists
static constexpr size_t OFF_ICURS  = 10568192;   // 262144 partition cursor bases
static constexpr size_t OFF_IROWS  = 10830336;   // 32772
static constexpr size_t OFF_ICNTO  = 10863108;   // 32768 out-degree totals
static constexpr size_t OFF_IESRC  = 10895876;   // 524288
// total 11420164 floats = 43.6 MiB (d_ws is 256 MiB)

__device__ __forceinline__ float selu_f(float x) {
  return 1.0507009873554805f * (x > 0.f ? x : 1.6732632423543772f * expm1f(x));
}

__device__ __forceinline__ float block_sum_bcast(float v, float* sm) {
  int lane = threadIdx.x & 63, w = threadIdx.x >> 6;
#pragma unroll
  for (int off = 32; off; off >>= 1) v += __shfl_down(v, off);
  __syncthreads();
  if (lane == 0) sm[w] = v;
  __syncthreads();
  return sm[0] + sm[1] + sm[2] + sm[3];
}

// ---- count: 128 blocks (graph x 8 partitions), private LDS hists -> global per-partition;
//      blocks 128..255: GraphNorm partials. No global atomics, no memset needed. ----
__global__ __launch_bounds__(1024) void k_count(const int* ei, const float* x,
                                                int* histin, int* histout,
                                                float* gsp, float* gsp2) { // grid 256 x 1024
  __shared__ int hin[2048], hout[2048];             // 16 KB
  __shared__ float l1[16][64], l2[16][64];          // 8 KB
  int blk = blockIdx.x;
  int tid = threadIdx.x;
  if (blk < 128) {
    int g = blk >> 3, p = blk & 7;
    int nbase = g * 2048, ebase = g * 32768 + p * 4096;
    hin[tid] = 0; hin[tid + 1024] = 0;
    hout[tid] = 0; hout[tid + 1024] = 0;
    __syncthreads();
#pragma unroll
    for (int it = 0; it < 4; it++) {
      int e = ebase + it * 1024 + tid;
      int s = ei[e], d = ei[E_ + e];
      atomicAdd(&hout[s - nbase], 1);
      atomicAdd(&hin[d - nbase], 1);
    }
    __syncthreads();
    histin[blk * 2048 + tid] = hin[tid];
    histin[blk * 2048 + tid + 1024] = hin[tid + 1024];
    histout[blk * 2048 + tid] = hout[tid];
    histout[blk * 2048 + tid + 1024] = hout[tid + 1024];
  } else {
    int gi = blk - 128;               // 0..127
    int b = gi >> 3, chunk = gi & 7;
    int c = tid & 63, r = tid >> 6;   // r: 0..15
    float s = 0.f, s2 = 0.f;
    const float* xb = x + ((size_t)b * N_ + (size_t)chunk * 256) * 64;
    for (int n = r; n < 256; n += 16) {
      float v = xb[n * 64 + c];
      s += v; s2 += v * v;
    }
    l1[r][c] = s; l2[r][c] = s2;
    __syncthreads();
    if (r == 0) {
      float t1 = 0.f, t2 = 0.f;
#pragma unroll
      for (int i = 0; i < 16; i++) { t1 += l1[i][c]; t2 += l2[i][c]; }
      gsp[gi * 64 + c] = t1;
      gsp2[gi * 64 + c] = t2;
    }
  }
}

// ---- scan: 16 blocks; totals over partitions, exclusive node scan -> rows,
//      per-partition cursor bases, dinv, out-degree totals ----
__global__ __launch_bounds__(1024) void k_scan(const int* histin, const int* histout,
                                               int* rows, int* cursp, int* cout_,
                                               float* dinv) {  // grid 16 x 1024
  __shared__ int sb[1024];
  int g = blockIdx.x, tid = threadIdx.x;
  int nbase = g * 2048, ebase = g * 32768;
  int n0 = 2 * tid, n1 = 2 * tid + 1;
  int h0[8], h1[8];
  int a = 0, b = 0, o0 = 0, o1 = 0;
#pragma unroll
  for (int p = 0; p < 8; p++) {
    h0[p] = histin[(g * 8 + p) * 2048 + n0];
    h1[p] = histin[(g * 8 + p) * 2048 + n1];
    a += h0[p]; b += h1[p];
    o0 += histout[(g * 8 + p) * 2048 + n0];
    o1 += histout[(g * 8 + p) * 2048 + n1];
  }
  sb[tid] = a + b;
  __syncthreads();
  for (int off = 1; off < 1024; off <<= 1) {
    int add = (tid >= off) ? sb[tid - off] : 0;
    __syncthreads();
    sb[tid] += add;
    __syncthreads();
  }
  int pref = (tid > 0) ? sb[tid - 1] : 0;
  int r0 = ebase + pref, r1 = r0 + a;
  rows[nbase + n0] = r0;
  rows[nbase + n1] = r1;
  dinv[nbase + n0] = rsqrtf((float)(a + 1));
  dinv[nbase + n1] = rsqrtf((float)(b + 1));
  cout_[nbase + n0] = o0;
  cout_[nbase + n1] = o1;
  int run0 = r0, run1 = r1;
#pragma unroll
  for (int p = 0; p < 8; p++) {
    cursp[(g * 8 + p) * 2048 + n0] = run0; run0 += h0[p];
    cursp[(g * 8 + p) * 2048 + n1] = run1; run1 += h1[p];
  }
  if (g == 15 && tid == 1023) rows[NT_] = E_;
}

// ---- fused: hsc = dinv*graphnorm(x) (blocks <2048) + bucket (128 blocks, LDS cursors) ----
__global__ __launch_bounds__(256) void k_prepb(const float* x, const float* gsp,
                                               const float* gsp2, const float* gw,
                                               const float* gb, const float* gms,
                                               const float* dinv, float* hsc,
                                               const int* ei, const int* cursp,
                                               int* esrc) { // grid 2176 x 256
  __shared__ float shs[64], scs[64];
  __shared__ int cur[2048];
  int tid = threadIdx.x;
  int blk = blockIdx.x;
  if (blk < 2048) {
    int bgr = blk >> 7;               // 16 nodes/block -> 128 blocks/graph
    if (tid < 64) {
      float s = 0.f, s2 = 0.f;
#pragma unroll
      for (int c8 = 0; c8 < 8; c8++) {
        s  += gsp[(bgr * 8 + c8) * 64 + tid];
        s2 += gsp2[(bgr * 8 + c8) * 64 + tid];
      }
      float mean = s * (1.f / 2048.f);
      float a = gms[tid];
      float var = s2 * (1.f / 2048.f) - (2.f * a - a * a) * mean * mean;
      shs[tid] = a * mean;
      scs[tid] = gw[tid] * rsqrtf(var + 1e-5f);
    }
    __syncthreads();
    int idx = blk * 256 + tid;
    int node = idx >> 4, g4 = (idx & 15) * 4;
    float di = dinv[node];
    float4 xv = *(const float4*)&x[(size_t)node * 64 + g4];
    float4 bb = *(const float4*)&gb[g4];
    float4 o;
    o.x = ((xv.x - shs[g4])     * scs[g4]     + bb.x) * di;
    o.y = ((xv.y - shs[g4 + 1]) * scs[g4 + 1] + bb.y) * di;
    o.z = ((xv.z - shs[g4 + 2]) * scs[g4 + 2] + bb.z) * di;
    o.w = ((xv.w - shs[g4 + 3]) * scs[g4 + 3] + bb.w) * di;
    *(float4*)&hsc[(size_t)node * 64 + g4] = o;
  } else {
    int bb = blk - 2048;              // 0..127: (graph, partition)
    int g = bb >> 3, p = bb & 7;
    int nbase = g * 2048;
    int ebase = g * 32768 + p * 4096;
    for (int i = tid; i < 2048; i += 256) cur[i] = cursp[bb * 2048 + i];
    __syncthreads();
#pragma unroll
    for (int it = 0; it < 16; it++) {
      int e = ebase + it * 256 + tid;
      int s = ei[e], d = ei[E_ + e];
      int pos = atomicAdd(&cur[d - nbase], 1);
      esrc[pos] = s;
    }
  }
}

// ---- fused CSR gather (8-deep MLP, 16-node blocks) + xd = selu(agg @ w1 + b1) ----
// 8-deep keeps VGPR ~68 (round-11's 16-deep hit 256 VGPR -> 11% occupancy);
// grid 2048 gives ~8 blocks/CU for latency hiding.
__global__ __launch_bounds__(256) void k_mm1(const float* hsc, const float* dinv,
                                             const int* rows, const int* esrc,
                                             const float* w1, const float* b1,
                                             float* xd) {  // grid 2048
  __shared__ float at[16 * 65];   // 4.2 KB
  int tid = threadIdx.x;
  int n0 = blockIdx.x * 16;
  int wv = tid >> 6, c = tid & 63;
  for (int i = 0; i < 4; i++) {
    int nn = i * 4 + wv;
    int node = n0 + nn;
    int e0 = rows[node], e1 = rows[node + 1];
    float dd = dinv[node];
    float acc = hsc[(size_t)node * 64 + c];
    for (int e = e0; e < e1; e += 8) {
      int sidx[8]; float wt[8], hv[8];
#pragma unroll
      for (int j = 0; j < 8; j++) {
        int ee = e + j;
        sidx[j] = esrc[ee < e1 ? ee : e0];
        wt[j] = (ee < e1) ? 1.f : 0.f;
      }
#pragma unroll
      for (int j = 0; j < 8; j++) hv[j] = hsc[(size_t)sidx[j] * 64 + c];
#pragma unroll
      for (int j = 0; j < 8; j++) acc += wt[j] * hv[j];
    }
    at[nn * 65 + c] = dd * acc;
  }
  __syncthreads();
  int tx = tid & 31, ty = tid >> 5;   // ty 0..7
  int f0 = tx * 4, nn = ty * 2;
  float acc[2][4] = {};
  for (int k = 0; k < 64; k++) {
    float4 wvv = *(const float4*)&w1[k * 128 + f0];
#pragma unroll
    for (int i = 0; i < 2; i++) {
      float av = at[(nn + i) * 65 + k];
      acc[i][0] += av * wvv.x; acc[i][1] += av * wvv.y;
      acc[i][2] += av * wvv.z; acc[i][3] += av * wvv.w;
    }
  }
  float4 bv = *(const float4*)&b1[f0];
#pragma unroll
  for (int i = 0; i < 2; i++) {
    float4 o;
    o.x = selu_f(acc[i][0] + bv.x);
    o.y = selu_f(acc[i][1] + bv.y);
    o.z = selu_f(acc[i][2] + bv.z);
    o.w = selu_f(acc[i][3] + bv.w);
    *(float4*)&xd[(size_t)(n0 + nn + i) * 128 + f0] = o;
  }
}

// ---- mega-fused: s = softmax(xd@w2+b2) + SS/ca/cs partials + s^T xd partial.
//      w2 read from global (16 KB, L1-resident) -> LDS 44 KB -> 3 blocks/CU. ----
__global__ __launch_bounds__(256) void k_mm2f(const float* xd, const float* w2,
                                              const float* b2, const int* cout_,
                                              float* s_ws, float* outs, float* ssp,
                                              float* cap, float* csp, float* part) {
  __shared__ float xt[64 * 129];    // 33 KB
  __shared__ float st[64 * 33];     // 8.4 KB
  __shared__ float r1[8][32], r2[8][32];
  int tid = threadIdx.x;
  int blk = blockIdx.x;
  int n0 = blk * 64;
  for (int i = tid; i < 2048; i += 256) {
    int n = i >> 5, j4 = (i & 31) * 4;
    float4 v = *(const float4*)&xd[(size_t)(n0 + n) * 128 + j4];
    xt[n * 129 + j4] = v.x; xt[n * 129 + j4 + 1] = v.y;
    xt[n * 129 + j4 + 2] = v.z; xt[n * 129 + j4 + 3] = v.w;
  }
  __syncthreads();
  int ty = tid >> 3;
  int k0 = (tid & 7) * 4;
  float acc2[2][4] = {};
  for (int j = 0; j < 128; j++) {
    float4 wv = *(const float4*)&w2[j * 32 + k0];
    float x0 = xt[(ty * 2) * 129 + j];
    float x1 = xt[(ty * 2 + 1) * 129 + j];
    acc2[0][0] += x0 * wv.x; acc2[0][1] += x0 * wv.y; acc2[0][2] += x0 * wv.z; acc2[0][3] += x0 * wv.w;
    acc2[1][0] += x1 * wv.x; acc2[1][1] += x1 * wv.y; acc2[1][2] += x1 * wv.z; acc2[1][3] += x1 * wv.w;
  }
  float4 bv2 = *(const float4*)&b2[k0];
#pragma unroll
  for (int i = 0; i < 2; i++) {
    int n = ty * 2 + i;
    st[n * 33 + k0]     = acc2[i][0] + bv2.x;
    st[n * 33 + k0 + 1] = acc2[i][1] + bv2.y;
    st[n * 33 + k0 + 2] = acc2[i][2] + bv2.z;
    st[n * 33 + k0 + 3] = acc2[i][3] + bv2.w;
  }
  __syncthreads();
  if (tid < 64) {
    float m = -3.4e38f;
    for (int kk = 0; kk < 32; kk++) m = fmaxf(m, st[tid * 33 + kk]);
    float ssum = 0.f;
    for (int kk = 0; kk < 32; kk++) {
      float e = expf(st[tid * 33 + kk] - m);
      st[tid * 33 + kk] = e; ssum += e;
    }
    float inv = 1.f / ssum;
    for (int kk = 0; kk < 32; kk++) st[tid * 33 + kk] *= inv;
  }
  __syncthreads();
  for (int i = tid; i < 512; i += 256) {
    int n = i >> 3, q = (i & 7) * 4;
    float4 o = {st[n * 33 + q], st[n * 33 + q + 1], st[n * 33 + q + 2], st[n * 33 + q + 3]};
    *(float4*)&s_ws[(size_t)(n0 + n) * 32 + q] = o;
    float* op = &outs[(size_t)(n0 + n) * 32 + q];
    op[0] = o.x; op[1] = o.y; op[2] = o.z; op[3] = o.w;
  }
  {
    int k = tid >> 3, l0 = (tid & 7) * 4;
    float a0 = 0, a1 = 0, a2 = 0, a3 = 0;
    for (int n = 0; n < 64; n++) {
      float sk = st[n * 33 + k];
      a0 += sk * st[n * 33 + l0];     a1 += sk * st[n * 33 + l0 + 1];
      a2 += sk * st[n * 33 + l0 + 2]; a3 += sk * st[n * 33 + l0 + 3];
    }
    float4 o = {a0, a1, a2, a3};
    *(float4*)&ssp[(size_t)blk * 1024 + k * 32 + l0] = o;
  }
  {
    int k2 = tid & 31, r = tid >> 5;
    float aca = 0.f, acs = 0.f;
    for (int i = 0; i < 8; i++) {
      int n = i * 8 + r;
      float dg = (float)cout_[n0 + n];
      float v = st[n * 33 + k2];
      acs += v; aca += v * dg;
    }
    r1[r][k2] = aca; r2[r][k2] = acs;
    __syncthreads();
    if (r == 0) {
      float sa = 0.f, sc = 0.f;
#pragma unroll
      for (int i = 0; i < 8; i++) { sa += r1[i][k2]; sc += r2[i][k2]; }
      cap[blk * 32 + k2] = sa;
      csp[blk * 32 + k2] = sc;
    }
  }
  {
    int tx = tid & 31, ty2 = tid >> 5;
    int f0 = tx * 4, kk0 = ty2 * 4;
    float acc[4][4] = {};
    for (int n = 0; n < 64; n++) {
      float s0 = st[n * 33 + kk0], s1 = st[n * 33 + kk0 + 1];
      float s2 = st[n * 33 + kk0 + 2], s3 = st[n * 33 + kk0 + 3];
      float4 xv = {xt[n * 129 + f0], xt[n * 129 + f0 + 1], xt[n * 129 + f0 + 2], xt[n * 129 + f0 + 3]};
      acc[0][0] += s0 * xv.x; acc[0][1] += s0 * xv.y; acc[0][2] += s0 * xv.z; acc[0][3] += s0 * xv.w;
      acc[1][0] += s1 * xv.x; acc[1][1] += s1 * xv.y; acc[1][2] += s1 * xv.z; acc[1][3] += s1 * xv.w;
      acc[2][0] += s2 * xv.x; acc[2][1] += s2 * xv.y; acc[2][2] += s2 * xv.z; acc[2][3] += s2 * xv.w;
      acc[3][0] += s3 * xv.x; acc[3][1] += s3 * xv.y; acc[3][2] += s3 * xv.z; acc[3][3] += s3 * xv.w;
    }
#pragma unroll
    for (int i = 0; i < 4; i++) {
      float4 o = {acc[i][0], acc[i][1], acc[i][2], acc[i][3]};
      *(float4*)&part[(size_t)(blk * 32 + kk0 + i) * 128 + f0] = o;
    }
  }
}

// ---- spec partials: per-edge dot of s rows; also zero loss ----
__global__ __launch_bounds__(256) void k_spec(const int* ei, const float* s_ws,
                                              float* specp, float* lossp) { // grid 512
  __shared__ float sm4[4];
  int blk = blockIdx.x, tid = threadIdx.x;
  if (blk == 0 && tid == 0) lossp[0] = 0.f;
  int ebase = blk * 1024;
  float acc = 0.f;
#pragma unroll
  for (int j = 0; j < 4; j++) {
    int e = ebase + j * 256 + tid;
    int s = ei[e], d = ei[E_ + e];
    const float4* ap = (const float4*)&s_ws[(size_t)s * 32];
    const float4* cp = (const float4*)&s_ws[(size_t)d * 32];
#pragma unroll
    for (int q = 0; q < 8; q++) {
      float4 u = ap[q], v = cp[q];
      acc += u.x * v.x + u.y * v.y + u.z * v.z + u.w * v.w;
    }
  }
  int lane = tid & 63, w = tid >> 6;
#pragma unroll
  for (int off = 32; off; off >>= 1) acc += __shfl_down(acc, off);
  if (lane == 0) sm4[w] = acc;
  __syncthreads();
  if (tid == 0) specp[blk] = sm4[0] + sm4[1] + sm4[2] + sm4[3];
}

// ---- fused: blocks <256 -> out reduce+selu+log_softmax (2 rows each); 256..271 -> losses ----
__global__ __launch_bounds__(256) void k_fin2(const float* part, const float* ssp,
                                              const float* csp, const float* cap,
                                              const float* specp, float* out0,
                                              float* loss) { // grid 272 x 256
  __shared__ float sred[4];
  int blk = blockIdx.x;
  int tid = threadIdx.x;
  if (blk < 256) {
    int half = tid >> 7;            // 0/1 -> two rows per block
    int f = tid & 127;
    int row = blk * 2 + half;
    int b = row >> 5, k = row & 31;
    float v = 0.f;
#pragma unroll
    for (int c = 0; c < 32; c++) v += part[(size_t)((b * 32 + c) * 32 + k) * 128 + f];
    v = selu_f(v);
    int lane = tid & 63, w = tid >> 6;
    float m = v;
#pragma unroll
    for (int off = 32; off; off >>= 1) m = fmaxf(m, __shfl_down(m, off));
    if (lane == 0) sred[w] = m;
    __syncthreads();
    m = fmaxf(sred[half * 2], sred[half * 2 + 1]);
    float e = expf(v - m);
    float t = e;
    __syncthreads();
#pragma unroll
    for (int off = 32; off; off >>= 1) t += __shfl_down(t, off);
    if (lane == 0) sred[w] = t;
    __syncthreads();
    float tot = sred[half * 2] + sred[half * 2 + 1];
    out0[(size_t)row * 128 + f] = v - m - logf(tot);
  } else {
    int b = blk - 256;
    float v0 = 0, v1 = 0, v2 = 0, v3 = 0;
    for (int c = 0; c < 32; c++) {
      float4 u = *(const float4*)&ssp[(size_t)(b * 32 + c) * 1024 + tid * 4];
      v0 += u.x; v1 += u.y; v2 += u.z; v3 += u.w;
    }
    float ssq = v0 * v0 + v1 * v1 + v2 * v2 + v3 * v3;
    ssq = block_sum_bcast(ssq, sred);
    float inv = 1.f / sqrtf(ssq);
    float dsq = 0.f;
    {
      int i0 = tid * 4;
      float vv[4] = {v0, v1, v2, v3};
#pragma unroll
      for (int jj = 0; jj < 4; jj++) {
        int i = i0 + jj;
        float d = vv[jj] * inv;
        if ((i >> 5) == (i & 31)) d -= 0.17677669529663687f;  // 1/sqrt(32)
        dsq += d * d;
      }
    }
    dsq = block_sum_bcast(dsq, sred);
    float csq = 0.f, casq = 0.f;
    if (tid < 32) {
      float c1 = 0.f, c2 = 0.f;
      for (int c = 0; c < 32; c++) {
        c1 += csp[(size_t)(b * 32 + c) * 32 + tid];
        c2 += cap[(size_t)(b * 32 + c) * 32 + tid];
      }
      csq = c1 * c1; casq = c2 * c2;
    }
    csq = block_sum_bcast(csq, sred);
    casq = block_sum_bcast(casq, sred);
    float spec_sum = (tid < 32) ? specp[b * 32 + tid] : 0.f;
    spec_sum = block_sum_bcast(spec_sum, sred);
    if (tid == 0) {
      float ortho = sqrtf(dsq);
      float cl = sqrtf(csq) * (1.f / 2048.f) * 5.656854249492381f - 1.f;
      float m = 16384.f;
      float spec = -(spec_sum - casq / (2.f * m)) / (2.f * m);
      atomicAdd(loss, (spec + ortho + cl) * (1.f / 16.f));
    }
  }
}

extern "C" void kernel_launch(void* const* d_in, const int* in_sizes, int n_in,
                              void* d_out, int out_size, void* d_ws, size_t ws_size,
                              hipStream_t stream) {
  (void)in_sizes; (void)n_in; (void)out_size; (void)ws_size;
  const float* x   = (const float*)d_in[0];
  const int*   ei  = (const int*)d_in[1];
  const float* gw  = (const float*)d_in[3];
  const float* gb  = (const float*)d_in[4];
  const float* gms = (const float*)d_in[5];
  const float* w1  = (const float*)d_in[6];
  const float* b1  = (const float*)d_in[7];
  const float* w2  = (const float*)d_in[8];
  const float* b2  = (const float*)d_in[9];
  float* out = (float*)d_out;
  float* ws  = (float*)d_ws;

  float* hsc    = ws + OFF_HSC;
  float* xd     = ws + OFF_XD;
  float* s_ws   = ws + OFF_SWS;
  float* part   = ws + OFF_PART;
  float* gsp    = ws + OFF_GSP;
  float* gsp2   = ws + OFF_GSP2;
  float* ssp    = ws + OFF_SSP;
  float* cap    = ws + OFF_CAP;
  float* csp    = ws + OFF_CSP;
  float* specp  = ws + OFF_SPECP;
  float* dinv   = ws + OFF_DINV;
  int*   histin = (int*)(ws + OFF_IHIN);
  int*   histout= (int*)(ws + OFF_IHOUT);
  int*   cursp  = (int*)(ws + OFF_ICURS);
  int*   rows   = (int*)(ws + OFF_IROWS);
  int*   cout_  = (int*)(ws + OFF_ICNTO);
  int*   esrc   = (int*)(ws + OFF_IESRC);

  float* out0  = out;            // [B,K,HID]
  float* lossp = out + 65536;    // scalar
  float* outs  = out + 65537;    // [B,N,K]

  hipLaunchKernelGGL(k_count, dim3(256), dim3(1024), 0, stream, ei, x, histin, histout, gsp, gsp2);
  hipLaunchKernelGGL(k_scan, dim3(16), dim3(1024), 0, stream,
                     histin, histout, rows, cursp, cout_, dinv);
  hipLaunchKernelGGL(k_prepb, dim3(2176), dim3(256), 0, stream,
                     x, gsp, gsp2, gw, gb, gms, dinv, hsc, ei, cursp, esrc);
  hipLaunchKernelGGL(k_mm1, dim3(2048), dim3(256), 0, stream, hsc, dinv, rows, esrc, w1, b1, xd);
  hipLaunchKernelGGL(k_mm2f, dim3(512), dim3(256), 0, stream,
                     xd, w2, b2, cout_, s_ws, outs, ssp, cap, csp, part);
  hipLaunchKernelGGL(k_spec, dim3(512), dim3(256), 0, stream, ei, s_ws, specp, lossp);
  hipLaunchKernelGGL(k_fin2, dim3(272), dim3(256), 0, stream,
                     part, ssp, csp, cap, specp, out0, lossp);
}

// Round 13
// 202.299 us; speedup vs baseline: 1.4341x; 1.4341x over previous
//
#include <hip/hip_runtime.h>
#include <cmath>

static constexpr int B_  = 16;
static constexpr int N_  = 2048;
static constexpr int NT_ = 32768;
static constexpr int E_  = 524288;

// Workspace layout (float-element offsets)
static constexpr size_t OFF_HSC    = 0;          // NT_*64
static constexpr size_t OFF_XD     = 2097152;    // NT_*128
static constexpr size_t OFF_SWS    = 6291456;    // NT_*32
static constexpr size_t OFF_PART   = 7340032;    // 512*32*128
static constexpr size_t OFF_GSP    = 9437184;    // 128*64
static constexpr size_t OFF_GSP2   = 9445376;    // 128*64
static constexpr size_t OFF_SSP    = 9453568;    // 512*1024
static constexpr size_t OFF_CAP    = 9977856;    // 512*32
static constexpr size_t OFF_CSP    = 9994240;    // 512*32
static constexpr size_t OFF_SPECP  = 10010624;   // 512
static constexpr size_t OFF_DINV   = 10011136;   // NT_
// int region
static constexpr size_t OFF_IHIN   = 10043904;   // 262144 per-partition in-hists
static constexpr size_t OFF_IHOUT  = 10306048;   // 262144 per-partition out-hists
static constexpr size_t OFF_ICURS  = 10568192;   // 262144 partition cursor bases
static constexpr size_t OFF_IROWS  = 10830336;   // 32772
static constexpr size_t OFF_ICNTO  = 10863108;   // 32768 out-degree totals
static constexpr size_t OFF_IESRC  = 10895876;   // 524288
// total 11420164 floats = 43.6 MiB (d_ws is 256 MiB)

__device__ __forceinline__ float selu_f(float x) {
  return 1.0507009873554805f * (x > 0.f ? x : 1.6732632423543772f * expm1f(x));
}

__device__ __forceinline__ float block_sum_bcast(float v, float* sm) {
  int lane = threadIdx.x & 63, w = threadIdx.x >> 6;
#pragma unroll
  for (int off = 32; off; off >>= 1) v += __shfl_down(v, off);
  __syncthreads();
  if (lane == 0) sm[w] = v;
  __syncthreads();
  return sm[0] + sm[1] + sm[2] + sm[3];
}

// ---- count: 128 blocks (graph x 8 partitions), private LDS hists -> global per-partition;
//      blocks 128..255: GraphNorm partials. No global atomics, no memset needed. ----
__global__ __launch_bounds__(1024) void k_count(const int* ei, const float* x,
                                                int* histin, int* histout,
                                                float* gsp, float* gsp2) { // grid 256 x 1024
  __shared__ int hin[2048], hout[2048];             // 16 KB
  __shared__ float l1[16][64], l2[16][64];          // 8 KB
  int blk = blockIdx.x;
  int tid = threadIdx.x;
  if (blk < 128) {
    int g = blk >> 3, p = blk & 7;
    int nbase = g * 2048, ebase = g * 32768 + p * 4096;
    hin[tid] = 0; hin[tid + 1024] = 0;
    hout[tid] = 0; hout[tid + 1024] = 0;
    __syncthreads();
#pragma unroll
    for (int it = 0; it < 4; it++) {
      int e = ebase + it * 1024 + tid;
      int s = ei[e], d = ei[E_ + e];
      atomicAdd(&hout[s - nbase], 1);
      atomicAdd(&hin[d - nbase], 1);
    }
    __syncthreads();
    histin[blk * 2048 + tid] = hin[tid];
    histin[blk * 2048 + tid + 1024] = hin[tid + 1024];
    histout[blk * 2048 + tid] = hout[tid];
    histout[blk * 2048 + tid + 1024] = hout[tid + 1024];
  } else {
    int gi = blk - 128;               // 0..127
    int b = gi >> 3, chunk = gi & 7;
    int c = tid & 63, r = tid >> 6;   // r: 0..15
    float s = 0.f, s2 = 0.f;
    const float* xb = x + ((size_t)b * N_ + (size_t)chunk * 256) * 64;
    for (int n = r; n < 256; n += 16) {
      float v = xb[n * 64 + c];
      s += v; s2 += v * v;
    }
    l1[r][c] = s; l2[r][c] = s2;
    __syncthreads();
    if (r == 0) {
      float t1 = 0.f, t2 = 0.f;
#pragma unroll
      for (int i = 0; i < 16; i++) { t1 += l1[i][c]; t2 += l2[i][c]; }
      gsp[gi * 64 + c] = t1;
      gsp2[gi * 64 + c] = t2;
    }
  }
}

// ---- scan: 16 blocks; totals over partitions, exclusive node scan -> rows,
//      per-partition cursor bases, dinv, out-degree totals ----
__global__ __launch_bounds__(1024) void k_scan(const int* histin, const int* histout,
                                               int* rows, int* cursp, int* cout_,
                                               float* dinv) {  // grid 16 x 1024
  __shared__ int sb[1024];
  int g = blockIdx.x, tid = threadIdx.x;
  int nbase = g * 2048, ebase = g * 32768;
  int n0 = 2 * tid, n1 = 2 * tid + 1;
  int h0[8], h1[8];
  int a = 0, b = 0, o0 = 0, o1 = 0;
#pragma unroll
  for (int p = 0; p < 8; p++) {
    h0[p] = histin[(g * 8 + p) * 2048 + n0];
    h1[p] = histin[(g * 8 + p) * 2048 + n1];
    a += h0[p]; b += h1[p];
    o0 += histout[(g * 8 + p) * 2048 + n0];
    o1 += histout[(g * 8 + p) * 2048 + n1];
  }
  sb[tid] = a + b;
  __syncthreads();
  for (int off = 1; off < 1024; off <<= 1) {
    int add = (tid >= off) ? sb[tid - off] : 0;
    __syncthreads();
    sb[tid] += add;
    __syncthreads();
  }
  int pref = (tid > 0) ? sb[tid - 1] : 0;
  int r0 = ebase + pref, r1 = r0 + a;
  rows[nbase + n0] = r0;
  rows[nbase + n1] = r1;
  dinv[nbase + n0] = rsqrtf((float)(a + 1));
  dinv[nbase + n1] = rsqrtf((float)(b + 1));
  cout_[nbase + n0] = o0;
  cout_[nbase + n1] = o1;
  int run0 = r0, run1 = r1;
#pragma unroll
  for (int p = 0; p < 8; p++) {
    cursp[(g * 8 + p) * 2048 + n0] = run0; run0 += h0[p];
    cursp[(g * 8 + p) * 2048 + n1] = run1; run1 += h1[p];
  }
  if (g == 15 && tid == 1023) rows[NT_] = E_;
}

// ---- fused: hsc = dinv*graphnorm(x) (blocks <2048) + bucket (128 blocks, LDS cursors) ----
__global__ __launch_bounds__(256) void k_prepb(const float* x, const float* gsp,
                                               const float* gsp2, const float* gw,
                                               const float* gb, const float* gms,
                                               const float* dinv, float* hsc,
                                               const int* ei, const int* cursp,
                                               int* esrc) { // grid 2176 x 256
  __shared__ float shs[64], scs[64];
  __shared__ int cur[2048];
  int tid = threadIdx.x;
  int blk = blockIdx.x;
  if (blk < 2048) {
    int bgr = blk >> 7;               // 16 nodes/block -> 128 blocks/graph
    if (tid < 64) {
      float s = 0.f, s2 = 0.f;
#pragma unroll
      for (int c8 = 0; c8 < 8; c8++) {
        s  += gsp[(bgr * 8 + c8) * 64 + tid];
        s2 += gsp2[(bgr * 8 + c8) * 64 + tid];
      }
      float mean = s * (1.f / 2048.f);
      float a = gms[tid];
      float var = s2 * (1.f / 2048.f) - (2.f * a - a * a) * mean * mean;
      shs[tid] = a * mean;
      scs[tid] = gw[tid] * rsqrtf(var + 1e-5f);
    }
    __syncthreads();
    int idx = blk * 256 + tid;
    int node = idx >> 4, g4 = (idx & 15) * 4;
    float di = dinv[node];
    float4 xv = *(const float4*)&x[(size_t)node * 64 + g4];
    float4 bb = *(const float4*)&gb[g4];
    float4 o;
    o.x = ((xv.x - shs[g4])     * scs[g4]     + bb.x) * di;
    o.y = ((xv.y - shs[g4 + 1]) * scs[g4 + 1] + bb.y) * di;
    o.z = ((xv.z - shs[g4 + 2]) * scs[g4 + 2] + bb.z) * di;
    o.w = ((xv.w - shs[g4 + 3]) * scs[g4 + 3] + bb.w) * di;
    *(float4*)&hsc[(size_t)node * 64 + g4] = o;
  } else {
    int bb = blk - 2048;              // 0..127: (graph, partition)
    int g = bb >> 3, p = bb & 7;
    int nbase = g * 2048;
    int ebase = g * 32768 + p * 4096;
    for (int i = tid; i < 2048; i += 256) cur[i] = cursp[bb * 2048 + i];
    __syncthreads();
#pragma unroll
    for (int it = 0; it < 16; it++) {
      int e = ebase + it * 256 + tid;
      int s = ei[e], d = ei[E_ + e];
      int pos = atomicAdd(&cur[d - nbase], 1);
      esrc[pos] = s;
    }
  }
}

// ---- fused CSR gather (8-deep MLP) + xd = selu(agg @ w1 + b1) ----
// Round-10 proven config: grid 1024, 32-node blocks, outer loop i<8 (NOT
// unrolled by compiler -> VGPR 68). Rounds 11/12's 16-node blocks (i<4)
// caused full outer unroll -> VGPR 256 -> 11% occupancy -> 145 us.
__global__ __launch_bounds__(256) void k_mm1(const float* hsc, const float* dinv,
                                             const int* rows, const int* esrc,
                                             const float* w1, const float* b1,
                                             float* xd) {  // grid 1024
  __shared__ float at[32 * 65];
  int tid = threadIdx.x;
  int n0 = blockIdx.x * 32;
  int wv = tid >> 6, c = tid & 63;
#pragma unroll 1
  for (int i = 0; i < 8; i++) {
    int nn = i * 4 + wv;
    int node = n0 + nn;
    int e0 = rows[node], e1 = rows[node + 1];
    float dd = dinv[node];
    float acc = hsc[(size_t)node * 64 + c];
    for (int e = e0; e < e1; e += 8) {
      int sidx[8]; float wt[8], hv[8];
#pragma unroll
      for (int j = 0; j < 8; j++) {
        int ee = e + j;
        sidx[j] = esrc[ee < e1 ? ee : e0];
        wt[j] = (ee < e1) ? 1.f : 0.f;
      }
#pragma unroll
      for (int j = 0; j < 8; j++) hv[j] = hsc[(size_t)sidx[j] * 64 + c];
#pragma unroll
      for (int j = 0; j < 8; j++) acc += wt[j] * hv[j];
    }
    at[nn * 65 + c] = dd * acc;
  }
  __syncthreads();
  int tx = tid & 31, ty = tid >> 5;
  int f0 = tx * 4, nn = ty * 4;
  float acc[4][4] = {};
  for (int k = 0; k < 64; k++) {
    float4 wvv = *(const float4*)&w1[k * 128 + f0];
#pragma unroll
    for (int i = 0; i < 4; i++) {
      float av = at[(nn + i) * 65 + k];
      acc[i][0] += av * wvv.x; acc[i][1] += av * wvv.y;
      acc[i][2] += av * wvv.z; acc[i][3] += av * wvv.w;
    }
  }
  float4 bv = *(const float4*)&b1[f0];
#pragma unroll
  for (int i = 0; i < 4; i++) {
    float4 o;
    o.x = selu_f(acc[i][0] + bv.x);
    o.y = selu_f(acc[i][1] + bv.y);
    o.z = selu_f(acc[i][2] + bv.z);
    o.w = selu_f(acc[i][3] + bv.w);
    *(float4*)&xd[(size_t)(n0 + nn + i) * 128 + f0] = o;
  }
}

// ---- mega-fused: s = softmax(xd@w2+b2) + SS/ca/cs partials + s^T xd partial.
//      w2 read from global (16 KB, L1-resident) -> LDS 44 KB -> 3 blocks/CU. ----
__global__ __launch_bounds__(256) void k_mm2f(const float* xd, const float* w2,
                                              const float* b2, const int* cout_,
                                              float* s_ws, float* outs, float* ssp,
                                              float* cap, float* csp, float* part) {
  __shared__ float xt[64 * 129];    // 33 KB
  __shared__ float st[64 * 33];     // 8.4 KB
  __shared__ float r1[8][32], r2[8][32];
  int tid = threadIdx.x;
  int blk = blockIdx.x;
  int n0 = blk * 64;
  for (int i = tid; i < 2048; i += 256) {
    int n = i >> 5, j4 = (i & 31) * 4;
    float4 v = *(const float4*)&xd[(size_t)(n0 + n) * 128 + j4];
    xt[n * 129 + j4] = v.x; xt[n * 129 + j4 + 1] = v.y;
    xt[n * 129 + j4 + 2] = v.z; xt[n * 129 + j4 + 3] = v.w;
  }
  __syncthreads();
  int ty = tid >> 3;
  int k0 = (tid & 7) * 4;
  float acc2[2][4] = {};
  for (int j = 0; j < 128; j++) {
    float4 wv = *(const float4*)&w2[j * 32 + k0];
    float x0 = xt[(ty * 2) * 129 + j];
    float x1 = xt[(ty * 2 + 1) * 129 + j];
    acc2[0][0] += x0 * wv.x; acc2[0][1] += x0 * wv.y; acc2[0][2] += x0 * wv.z; acc2[0][3] += x0 * wv.w;
    acc2[1][0] += x1 * wv.x; acc2[1][1] += x1 * wv.y; acc2[1][2] += x1 * wv.z; acc2[1][3] += x1 * wv.w;
  }
  float4 bv2 = *(const float4*)&b2[k0];
#pragma unroll
  for (int i = 0; i < 2; i++) {
    int n = ty * 2 + i;
    st[n * 33 + k0]     = acc2[i][0] + bv2.x;
    st[n * 33 + k0 + 1] = acc2[i][1] + bv2.y;
    st[n * 33 + k0 + 2] = acc2[i][2] + bv2.z;
    st[n * 33 + k0 + 3] = acc2[i][3] + bv2.w;
  }
  __syncthreads();
  if (tid < 64) {
    float m = -3.4e38f;
    for (int kk = 0; kk < 32; kk++) m = fmaxf(m, st[tid * 33 + kk]);
    float ssum = 0.f;
    for (int kk = 0; kk < 32; kk++) {
      float e = expf(st[tid * 33 + kk] - m);
      st[tid * 33 + kk] = e; ssum += e;
    }
    float inv = 1.f / ssum;
    for (int kk = 0; kk < 32; kk++) st[tid * 33 + kk] *= inv;
  }
  __syncthreads();
  for (int i = tid; i < 512; i += 256) {
    int n = i >> 3, q = (i & 7) * 4;
    float4 o = {st[n * 33 + q], st[n * 33 + q + 1], st[n * 33 + q + 2], st[n * 33 + q + 3]};
    *(float4*)&s_ws[(size_t)(n0 + n) * 32 + q] = o;
    float* op = &outs[(size_t)(n0 + n) * 32 + q];
    op[0] = o.x; op[1] = o.y; op[2] = o.z; op[3] = o.w;
  }
  {
    int k = tid >> 3, l0 = (tid & 7) * 4;
    float a0 = 0, a1 = 0, a2 = 0, a3 = 0;
    for (int n = 0; n < 64; n++) {
      float sk = st[n * 33 + k];
      a0 += sk * st[n * 33 + l0];     a1 += sk * st[n * 33 + l0 + 1];
      a2 += sk * st[n * 33 + l0 + 2]; a3 += sk * st[n * 33 + l0 + 3];
    }
    float4 o = {a0, a1, a2, a3};
    *(float4*)&ssp[(size_t)blk * 1024 + k * 32 + l0] = o;
  }
  {
    int k2 = tid & 31, r = tid >> 5;
    float aca = 0.f, acs = 0.f;
    for (int i = 0; i < 8; i++) {
      int n = i * 8 + r;
      float dg = (float)cout_[n0 + n];
      float v = st[n * 33 + k2];
      acs += v; aca += v * dg;
    }
    r1[r][k2] = aca; r2[r][k2] = acs;
    __syncthreads();
    if (r == 0) {
      float sa = 0.f, sc = 0.f;
#pragma unroll
      for (int i = 0; i < 8; i++) { sa += r1[i][k2]; sc += r2[i][k2]; }
      cap[blk * 32 + k2] = sa;
      csp[blk * 32 + k2] = sc;
    }
  }
  {
    int tx = tid & 31, ty2 = tid >> 5;
    int f0 = tx * 4, kk0 = ty2 * 4;
    float acc[4][4] = {};
    for (int n = 0; n < 64; n++) {
      float s0 = st[n * 33 + kk0], s1 = st[n * 33 + kk0 + 1];
      float s2 = st[n * 33 + kk0 + 2], s3 = st[n * 33 + kk0 + 3];
      float4 xv = {xt[n * 129 + f0], xt[n * 129 + f0 + 1], xt[n * 129 + f0 + 2], xt[n * 129 + f0 + 3]};
      acc[0][0] += s0 * xv.x; acc[0][1] += s0 * xv.y; acc[0][2] += s0 * xv.z; acc[0][3] += s0 * xv.w;
      acc[1][0] += s1 * xv.x; acc[1][1] += s1 * xv.y; acc[1][2] += s1 * xv.z; acc[1][3] += s1 * xv.w;
      acc[2][0] += s2 * xv.x; acc[2][1] += s2 * xv.y; acc[2][2] += s2 * xv.z; acc[2][3] += s2 * xv.w;
      acc[3][0] += s3 * xv.x; acc[3][1] += s3 * xv.y; acc[3][2] += s3 * xv.z; acc[3][3] += s3 * xv.w;
    }
#pragma unroll
    for (int i = 0; i < 4; i++) {
      float4 o = {acc[i][0], acc[i][1], acc[i][2], acc[i][3]};
      *(float4*)&part[(size_t)(blk * 32 + kk0 + i) * 128 + f0] = o;
    }
  }
}

// ---- spec partials: per-edge dot of s rows; also zero loss ----
__global__ __launch_bounds__(256) void k_spec(const int* ei, const float* s_ws,
                                              float* specp, float* lossp) { // grid 512
  __shared__ float sm4[4];
  int blk = blockIdx.x, tid = threadIdx.x;
  if (blk == 0 && tid == 0) lossp[0] = 0.f;
  int ebase = blk * 1024;
  float acc = 0.f;
#pragma unroll
  for (int j = 0; j < 4; j++) {
    int e = ebase + j * 256 + tid;
    int s = ei[e], d = ei[E_ + e];
    const float4* ap = (const float4*)&s_ws[(size_t)s * 32];
    const float4* cp = (const float4*)&s_ws[(size_t)d * 32];
#pragma unroll
    for (int q = 0; q < 8; q++) {
      float4 u = ap[q], v = cp[q];
      acc += u.x * v.x + u.y * v.y + u.z * v.z + u.w * v.w;
    }
  }
  int lane = tid & 63, w = tid >> 6;
#pragma unroll
  for (int off = 32; off; off >>= 1) acc += __shfl_down(acc, off);
  if (lane == 0) sm4[w] = acc;
  __syncthreads();
  if (tid == 0) specp[blk] = sm4[0] + sm4[1] + sm4[2] + sm4[3];
}

// ---- fused: blocks <256 -> out reduce+selu+log_softmax (2 rows each); 256..271 -> losses ----
__global__ __launch_bounds__(256) void k_fin2(const float* part, const float* ssp,
                                              const float* csp, const float* cap,
                                              const float* specp, float* out0,
                                              float* loss) { // grid 272 x 256
  __shared__ float sred[4];
  int blk = blockIdx.x;
  int tid = threadIdx.x;
  if (blk < 256) {
    int half = tid >> 7;            // 0/1 -> two rows per block
    int f = tid & 127;
    int row = blk * 2 + half;
    int b = row >> 5, k = row & 31;
    float v = 0.f;
#pragma unroll
    for (int c = 0; c < 32; c++) v += part[(size_t)((b * 32 + c) * 32 + k) * 128 + f];
    v = selu_f(v);
    int lane = tid & 63, w = tid >> 6;
    float m = v;
#pragma unroll
    for (int off = 32; off; off >>= 1) m = fmaxf(m, __shfl_down(m, off));
    if (lane == 0) sred[w] = m;
    __syncthreads();
    m = fmaxf(sred[half * 2], sred[half * 2 + 1]);
    float e = expf(v - m);
    float t = e;
    __syncthreads();
#pragma unroll
    for (int off = 32; off; off >>= 1) t += __shfl_down(t, off);
    if (lane == 0) sred[w] = t;
    __syncthreads();
    float tot = sred[half * 2] + sred[half * 2 + 1];
    out0[(size_t)row * 128 + f] = v - m - logf(tot);
  } else {
    int b = blk - 256;
    float v0 = 0, v1 = 0, v2 = 0, v3 = 0;
    for (int c = 0; c < 32; c++) {
      float4 u = *(const float4*)&ssp[(size_t)(b * 32 + c) * 1024 + tid * 4];
      v0 += u.x; v1 += u.y; v2 += u.z; v3 += u.w;
    }
    float ssq = v0 * v0 + v1 * v1 + v2 * v2 + v3 * v3;
    ssq = block_sum_bcast(ssq, sred);
    float inv = 1.f / sqrtf(ssq);
    float dsq = 0.f;
    {
      int i0 = tid * 4;
      float vv[4] = {v0, v1, v2, v3};
#pragma unroll
      for (int jj = 0; jj < 4; jj++) {
        int i = i0 + jj;
        float d = vv[jj] * inv;
        if ((i >> 5) == (i & 31)) d -= 0.17677669529663687f;  // 1/sqrt(32)
        dsq += d * d;
      }
    }
    dsq = block_sum_bcast(dsq, sred);
    float csq = 0.f, casq = 0.f;
    if (tid < 32) {
      float c1 = 0.f, c2 = 0.f;
      for (int c = 0; c < 32; c++) {
        c1 += csp[(size_t)(b * 32 + c) * 32 + tid];
        c2 += cap[(size_t)(b * 32 + c) * 32 + tid];
      }
      csq = c1 * c1; casq = c2 * c2;
    }
    csq = block_sum_bcast(csq, sred);
    casq = block_sum_bcast(casq, sred);
    float spec_sum = (tid < 32) ? specp[b * 32 + tid] : 0.f;
    spec_sum = block_sum_bcast(spec_sum, sred);
    if (tid == 0) {
      float ortho = sqrtf(dsq);
      float cl = sqrtf(csq) * (1.f / 2048.f) * 5.656854249492381f - 1.f;
      float m = 16384.f;
      float spec = -(spec_sum - casq / (2.f * m)) / (2.f * m);
      atomicAdd(loss, (spec + ortho + cl) * (1.f / 16.f));
    }
  }
}

extern "C" void kernel_launch(void* const* d_in, const int* in_sizes, int n_in,
                              void* d_out, int out_size, void* d_ws, size_t ws_size,
                              hipStream_t stream) {
  (void)in_sizes; (void)n_in; (void)out_size; (void)ws_size;
  const float* x   = (const float*)d_in[0];
  const int*   ei  = (const int*)d_in[1];
  const float* gw  = (const float*)d_in[3];
  const float* gb  = (const float*)d_in[4];
  const float* gms = (const float*)d_in[5];
  const float* w1  = (const float*)d_in[6];
  const float* b1  = (const float*)d_in[7];
  const float* w2  = (const float*)d_in[8];
  const float* b2  = (const float*)d_in[9];
  float* out = (float*)d_out;
  float* ws  = (float*)d_ws;

  float* hsc    = ws + OFF_HSC;
  float* xd     = ws + OFF_XD;
  float* s_ws   = ws + OFF_SWS;
  float* part   = ws + OFF_PART;
  float* gsp    = ws + OFF_GSP;
  float* gsp2   = ws + OFF_GSP2;
  float* ssp    = ws + OFF_SSP;
  float* cap    = ws + OFF_CAP;
  float* csp    = ws + OFF_CSP;
  float* specp  = ws + OFF_SPECP;
  float* dinv   = ws + OFF_DINV;
  int*   histin = (int*)(ws + OFF_IHIN);
  int*   histout= (int*)(ws + OFF_IHOUT);
  int*   cursp  = (int*)(ws + OFF_ICURS);
  int*   rows   = (int*)(ws + OFF_IROWS);
  int*   cout_  = (int*)(ws + OFF_ICNTO);
  int*   esrc   = (int*)(ws + OFF_IESRC);

  float* out0  = out;            // [B,K,HID]
  float* lossp = out + 65536;    // scalar
  float* outs  = out + 65537;    // [B,N,K]

  hipLaunchKernelGGL(k_count, dim3(256), dim3(1024), 0, stream, ei, x, histin, histout, gsp, gsp2);
  hipLaunchKernelGGL(k_scan, dim3(16), dim3(1024), 0, stream,
                     histin, histout, rows, cursp, cout_, dinv);
  hipLaunchKernelGGL(k_prepb, dim3(2176), dim3(256), 0, stream,
                     x, gsp, gsp2, gw, gb, gms, dinv, hsc, ei, cursp, esrc);
  hipLaunchKernelGGL(k_mm1, dim3(1024), dim3(256), 0, stream, hsc, dinv, rows, esrc, w1, b1, xd);
  hipLaunchKernelGGL(k_mm2f, dim3(512), dim3(256), 0, stream,
                     xd, w2, b2, cout_, s_ws, outs, ssp, cap, csp, part);
  hipLaunchKernelGGL(k_spec, dim3(512), dim3(256), 0, stream, ei, s_ws, specp, lossp);
  hipLaunchKernelGGL(k_fin2, dim3(272), dim3(256), 0, stream,
                     part, ssp, csp, cap, specp, out0, lossp);
}